// Round 5
// baseline (374.508 us; speedup 1.0000x reference)
//
#include <hip/hip_runtime.h>
#include <hip/hip_bf16.h>

typedef short bf16x8 __attribute__((ext_vector_type(8)));
typedef short bf16x4 __attribute__((ext_vector_type(4)));
typedef float f32x4  __attribute__((ext_vector_type(4)));

static constexpr int Bb   = 128;
static constexpr int Cin  = 32;
static constexpr int Nn   = 325;
static constexpr int Tt   = 24;
static constexpr int Cout = 64;
static constexpr int NKS  = 11;    // K steps (352 = 11*32)
static constexpr int WP   = 336;   // padded w rows in stpb
static constexpr int NWT  = 21;
static constexpr int TH   = 8;     // t per block (3 slices)
static constexpr int CTB  = TH * Cin;          // 256 ct rows per block
static constexpr size_t XTB_ELEMS = (size_t)Bb * NKS * (Tt * Cin) * 32;
static constexpr size_t STP_ELEMS = (size_t)4 * NKS * WP * 32;
static constexpr size_t WB_ELEMS  = (size_t)Cout * 128;

__device__ __forceinline__ void gld16(const void* g, void* l) {
    __builtin_amdgcn_global_load_lds(
        (const __attribute__((address_space(1))) void*)g,
        (__attribute__((address_space(3))) void*)l, 16, 0, 0);
}
__device__ __forceinline__ short bfb(float f) {
    __hip_bfloat16 h = __float2bfloat16(f);
    return *reinterpret_cast<short*>(&h);
}

// ---------- P1: stpb[e][ks][w(336)][vi(32)] bf16, identity-augmented ------
__global__ void build_stp(const float* __restrict__ sup,
                          __hip_bfloat16* __restrict__ stpb) {
    int idx = blockIdx.x * 256 + threadIdx.x;
    int total = 4 * NKS * WP * 32;
    if (idx >= total) return;
    int e  = idx / (NKS * WP * 32);
    int r  = idx % (NKS * WP * 32);
    int ks = r / (WP * 32);
    int r2 = r % (WP * 32);
    int w  = r2 / 32;
    int vi = r2 % 32;
    int v  = ks * 32 + vi;
    float val = 0.f;
    if (e == 0) {
        val = (v == w && v < Nn) ? 1.f : 0.f;
    } else if (v < Nn && w < Nn) {
        val = sup[((size_t)(e - 1) * Nn + v) * Nn + w];
    }
    stpb[idx] = __float2bfloat16(val);
}

// ---------- P1b: W fp32 -> bf16 [64][128] ---------------------------------
__global__ void build_wb(const float* __restrict__ W,
                         __hip_bfloat16* __restrict__ Wb) {
    int i = blockIdx.x * 256 + threadIdx.x;
    if (i < Cout * 128) Wb[i] = __float2bfloat16(W[i]);
}

// ---------- P2: x[b][c][v][t] -> xTb[b][ks][ct=t*32+c][vi(32)] bf16 -------
__global__ void transpose_x(const float* __restrict__ x,
                            __hip_bfloat16* __restrict__ xTb) {
    __shared__ __hip_bfloat16 ls[Cin * 32 * 28];   // [c][vi][28] 57344 B
    int b  = blockIdx.x / NKS;
    int ks = blockIdx.x % NKS;
    int tid = threadIdx.x;
    // phase 1: coalesced float4 reads (4 t's), pack bf16x4 -> LDS
    for (int i = 0; i < 24; ++i) {
        int f4 = i * 256 + tid;                    // 6144 float4 chunks
        int c  = f4 / 192;
        int rm = f4 % 192;
        int vi = rm / 6;
        int t0 = (rm % 6) * 4;
        int v  = ks * 32 + vi;
        float4 val = make_float4(0.f, 0.f, 0.f, 0.f);
        if (v < Nn)
            val = *(const float4*)(x + (((size_t)(b * Cin + c) * Nn + v) * Tt + t0));
        bf16x4 pk = { bfb(val.x), bfb(val.y), bfb(val.z), bfb(val.w) };
        *(bf16x4*)&ls[(c * 32 + vi) * 28 + t0] = pk;
    }
    __syncthreads();
    // phase 2: gather 8 vi's per 16B chunk, contiguous global store
    for (int j = 0; j < 12; ++j) {
        int o    = j * 256 + tid;                  // 3072 16B chunks
        int row  = o >> 2;                         // ct = t*32+c
        int slot = o & 3;
        int t = row >> 5, c = row & 31;
        union { short us[8]; bf16x8 v8; } pk;
#pragma unroll
        for (int q = 0; q < 8; ++q) {
            __hip_bfloat16 h = ls[(c * 32 + slot * 8 + q) * 28 + t];
            pk.us[q] = *reinterpret_cast<short*>(&h);
        }
        *(bf16x8*)((char*)xTb + ((size_t)(b * NKS + ks) * 768 + row) * 64 + slot * 16) = pk.v8;
    }
}

// ---------- M: block=(b,th,wt); contiguous K-blocked staging --------------
__global__ __launch_bounds__(256, 3) void graphconv_main(
    const __hip_bfloat16* __restrict__ xTb,
    const __hip_bfloat16* __restrict__ stpb,
    const __hip_bfloat16* __restrict__ Wb,
    const float* __restrict__ bias,
    float* __restrict__ out) {
    __shared__ alignas(16) __hip_bfloat16 Xs[2][CTB * 32];  // 2 x 16384 B
    __shared__ alignas(16) __hip_bfloat16 Ss[2][64 * 32];   // 2 x 4096 B

    // bijective XCD swizzle: 8064 = 8*1008; wt innermost (X-slice L2 reuse)
    int bid = blockIdx.x;
    int lg  = (bid & 7) * 1008 + (bid >> 3);
    int b   = lg / 63;
    int r   = lg % 63;
    int th  = r / NWT;
    int wt  = r % NWT;
    int w0  = wt * 16, t0 = th * TH, ct0 = th * CTB;

    int tid = threadIdx.x, wid = tid >> 6, lane = tid & 63;
    int cl = lane & 15, kg = lane >> 4;

    // staging constants: pre-swizzled SOURCE slot (within 64B rows -> free)
    int srow   = lane >> 2;
    int sslotB = (((lane & 3) ^ ((lane >> 3) & 3)) << 4);
    int xsw    = ((kg ^ ((cl >> 1) & 3)) << 4);   // read-side swizzle

    const char* xslab = (const char*)xTb + (size_t)b * NKS * 768 * 64;
    const char* sslab = (const char*)stpb;

    // ---- stage K-step 0 ----
#pragma unroll
    for (int ii = 0; ii < 4; ++ii) {
        int ch = wid * 4 + ii;
        gld16(xslab + (size_t)(ct0 + ch * 16 + srow) * 64 + sslotB,
              (char*)&Xs[0][0] + ch * 1024 + lane * 16);
    }
    gld16(sslab + (size_t)((wid * NKS + 0) * WP + w0 + srow) * 64 + sslotB,
          (char*)&Ss[0][0] + wid * 1024 + lane * 16);
    __syncthreads();

    // ---- GEMM1: Y^T[ct][w], double-buffered, contiguous staging ----
    f32x4 acc1[4][4] = {};
    int bb = 0;
    for (int ks = 0; ks < NKS; ++ks) {
        if (ks + 1 < NKS) {
#pragma unroll
            for (int ii = 0; ii < 4; ++ii) {
                int ch = wid * 4 + ii;
                gld16(xslab + (size_t)(ks + 1) * 768 * 64 +
                          (size_t)(ct0 + ch * 16 + srow) * 64 + sslotB,
                      (char*)&Xs[bb ^ 1][0] + ch * 1024 + lane * 16);
            }
            gld16(sslab + (size_t)((wid * NKS + ks + 1) * WP + w0 + srow) * 64 + sslotB,
                  (char*)&Ss[bb ^ 1][0] + wid * 1024 + lane * 16);
        }
        bf16x8 xf[4], af[4];
#pragma unroll
        for (int j = 0; j < 4; ++j)
            xf[j] = *(const bf16x8*)((const char*)&Xs[bb][0] +
                                     (((wid * 4 + j) * 16 + cl) << 6) + xsw);
#pragma unroll
        for (int e = 0; e < 4; ++e)
            af[e] = *(const bf16x8*)((const char*)&Ss[bb][0] +
                                     ((e * 16 + cl) << 6) + xsw);
#pragma unroll
        for (int e = 0; e < 4; ++e)
#pragma unroll
            for (int j = 0; j < 4; ++j)
                acc1[e][j] = __builtin_amdgcn_mfma_f32_16x16x32_bf16(
                    xf[j], af[e], acc1[e][j], 0, 0, 0);
        __syncthreads();
        bb ^= 1;
    }

    // ---- GEMM2 from registers: kappa = e*2 + (j&1), tj = j>>1 ----
    f32x4 acc2[4][2] = {};
#pragma unroll
    for (int kappa = 0; kappa < 8; ++kappa) {
        int e = kappa >> 1, half = kappa & 1;
        bf16x4 wf[4];
#pragma unroll
        for (int mt = 0; mt < 4; ++mt)
            wf[mt] = *(const bf16x4*)((const char*)Wb + (mt * 16 + cl) * 256 +
                                      kappa * 32 + kg * 8);
#pragma unroll
        for (int tj = 0; tj < 2; ++tj) {
            int j = tj * 2 + half;
            f32x4 y = acc1[e][j];
            bf16x4 pb = { bfb(y[0]), bfb(y[1]), bfb(y[2]), bfb(y[3]) };
#pragma unroll
            for (int mt = 0; mt < 4; ++mt)
                acc2[mt][tj] = __builtin_amdgcn_mfma_f32_16x16x16bf16_1k(
                    wf[mt], pb, acc2[mt][tj], 0, 0, 0);
        }
    }

    // ---- epilogue: col=cl -> w, row=kg*4+r -> o; t = t0 + wid*2 + tj ----
    int w = w0 + cl;
    if (w < Nn) {
#pragma unroll
        for (int mt = 0; mt < 4; ++mt) {
            float4 bv = *(const float4*)&bias[mt * 16 + kg * 4];
#pragma unroll
            for (int r2_ = 0; r2_ < 4; ++r2_) {
                int o = mt * 16 + kg * 4 + r2_;
                float bvr = (r2_ == 0) ? bv.x : (r2_ == 1) ? bv.y : (r2_ == 2) ? bv.z : bv.w;
                size_t base = ((size_t)(b * Cout + o) * Nn + w) * Tt + t0 + wid * 2;
#pragma unroll
                for (int tj = 0; tj < 2; ++tj)
                    out[base + tj] = acc2[mt][tj][r2_] + bvr;
            }
        }
    }
}

extern "C" void kernel_launch(void* const* d_in, const int* in_sizes, int n_in,
                              void* d_out, int out_size, void* d_ws, size_t ws_size,
                              hipStream_t stream) {
    const float* x    = (const float*)d_in[0];
    const float* sup  = (const float*)d_in[1];
    const float* W    = (const float*)d_in[2];
    const float* bias = (const float*)d_in[3];
    float* out = (float*)d_out;

    __hip_bfloat16* xTb  = (__hip_bfloat16*)d_ws;
    __hip_bfloat16* stpb = xTb + XTB_ELEMS;
    __hip_bfloat16* Wb   = stpb + STP_ELEMS;

    build_stp<<<(int)((STP_ELEMS + 255) / 256), 256, 0, stream>>>(sup, stpb);
    build_wb<<<(int)((WB_ELEMS + 255) / 256), 256, 0, stream>>>(W, Wb);
    transpose_x<<<Bb * NKS, 256, 0, stream>>>(x, xTb);
    graphconv_main<<<Bb * 3 * NWT, 256, 0, stream>>>(xTb, stpb, Wb, bias, out);
}